// Round 10
// baseline (31.986 us; speedup 1.0000x reference)
//
#include <hip/hip_runtime.h>
#include <hip/hip_bf16.h>

#define NN 2048   // n_nodes
#define CC 512    // channels

typedef __bf16 bf16x8 __attribute__((ext_vector_type(8)));
typedef float  f32x4  __attribute__((ext_vector_type(4)));
typedef int    i32x4  __attribute__((ext_vector_type(4)));
typedef unsigned short u16x4 __attribute__((ext_vector_type(4)));

#define GLD_LDS16(gptr, lptr)                                                        \
    __builtin_amdgcn_global_load_lds(                                                \
        (const __attribute__((address_space(1))) void*)(gptr),                       \
        (__attribute__((address_space(3))) void*)(lptr), 16, 0, 0)

__device__ __forceinline__ unsigned short f2bf(float f) {
    unsigned int u = __builtin_bit_cast(unsigned int, f);
    u += 0x7FFFu + ((u >> 16) & 1u);
    return (unsigned short)(u >> 16);
}
__device__ __forceinline__ float bf2f(unsigned short u) {
    unsigned int v = (unsigned int)u << 16;
    return __builtin_bit_cast(float, v);
}

// Packed operand layout = exact LDS image the GEMM consumes:
//   pack[tile][w:8][kt:8][granule:256][8 shorts],  granule = row*4 + slot,
//   content(row,slot,e) = M[tile*64+row][w*256 + kt*32 + kb*8 + e],  kb = (slot-(row>>1))&3.

// ---- prep (unchanged from round 9): L -> Lpack (XCD-aligned), x -> Apack ----
__global__ __launch_bounds__(256)
void prep_kernel(const float* __restrict__ L, unsigned short* __restrict__ Lpack,
                 const float* __restrict__ x, unsigned short* __restrict__ Apack) {
    __shared__ unsigned short sbuf[256 * 72];   // 36 KB
    const int tid = threadIdx.x;
    if (blockIdx.x < 256) {
        unsigned short (*tile)[264] = (unsigned short(*)[264])sbuf;
        int j  = blockIdx.x >> 3;
        int nt = (blockIdx.x & 7) * 4 + (j & 3);
        int w  = j >> 2;
        #pragma unroll
        for (int it = 0; it < 16; ++it) {
            int r = it * 4 + (tid >> 6);
            int c = (tid & 63) * 4;
            f32x4 v = __builtin_nontemporal_load(
                (const f32x4*)(L + (size_t)(nt * 64 + r) * NN + w * 256 + c));
            u16x4 o;
            o[0] = f2bf(v[0]); o[1] = f2bf(v[1]); o[2] = f2bf(v[2]); o[3] = f2bf(v[3]);
            *(u16x4*)&tile[r][c] = o;
        }
        __syncthreads();
        unsigned short* outp = Lpack + (size_t)(nt * 8 + w) * 8 * 2048;
        int row = tid >> 2, slot = tid & 3;
        int kb  = (slot - (row >> 1)) & 3;
        #pragma unroll
        for (int kt = 0; kt < 8; ++kt) {
            i32x4 v = *(const i32x4*)&tile[row][kt * 32 + kb * 8];
            *(i32x4*)(outp + kt * 2048 + tid * 8) = v;
        }
    } else {
        unsigned short (*t2)[72] = (unsigned short(*)[72])sbuf;
        int b2 = blockIdx.x - 256;
        int mt = b2 >> 3, w = b2 & 7;
        #pragma unroll
        for (int it = 0; it < 16; ++it) {
            int r = it * 16 + (tid >> 4);
            int c = (tid & 15) * 4;
            f32x4 v = *(const f32x4*)(x + (size_t)(w * 256 + r) * CC + mt * 64 + c);
            t2[r][c] = f2bf(v[0]); t2[r][c + 1] = f2bf(v[1]);
            t2[r][c + 2] = f2bf(v[2]); t2[r][c + 3] = f2bf(v[3]);
        }
        __syncthreads();
        unsigned short* outp = Apack + (size_t)(mt * 8 + w) * 8 * 2048;
        int row = tid >> 2, slot = tid & 3;
        int kb  = (slot - (row >> 1)) & 3;
        #pragma unroll
        for (int kt = 0; kt < 8; ++kt) {
            unsigned short tmp[8];
            #pragma unroll
            for (int e = 0; e < 8; ++e) tmp[e] = t2[kt * 32 + kb * 8 + e][row];
            *(i32x4*)(outp + kt * 2048 + tid * 8) = *(const i32x4*)tmp;
        }
    }
}

// ---- GEMM w = v @ L, 64x64 tile, 8 waves with disjoint 256-wide K-chunks.
//      A: persistent VGPRs, loaded direct from packed global (fully COALESCED
//         1KB-permutation loads; 2 generations of 16).  B: 4-deep per-wave LDS
//      buffer via contiguous global_load_lds; ds_read pipelined one iter ahead
//      (counted lgkmcnt(4)); counted vmcnt; zero barriers in main loop.
//      PHASE 1: w1pk = bf16(w)   (LDS-staged, coalesced 16B/thread store)
//      PHASE 2: out[n][c] = c0*x + C1*w1 + C2*w2  (LDS-staged coalesced) ----
template <int PHASE>
__global__ __launch_bounds__(512, 2)
void gemm_step_kernel(const unsigned short* __restrict__ Apk,  // packed A [8][8][8][2048] (phase2: w1pk)
                      const unsigned short* __restrict__ Bpk,  // packed L [32][8][8][2048]
                      const float* __restrict__ xin,           // x [2048][512] (phase2)
                      unsigned short* __restrict__ w1pk,       // packed w1 out (phase1)
                      float* __restrict__ out,                 // [2048][512] (phase2)
                      const float* __restrict__ tptr) {
    __shared__ short lds[65536];   // 8 waves x 16KB (4 B-bufs x 4KB); reused in epilogue

    const int tid  = threadIdx.x;
    const int lane = tid & 63;
    const int wid  = tid >> 6;

    const int bid = blockIdx.x;
    const int xcd = bid & 7, idx = bid >> 3;
    const int n0  = (xcd * 4 + (idx & 3)) * 64;
    const int m0  = (idx >> 2) * 64;
    const int mt  = m0 >> 6, nt = n0 >> 6;

    short* wbase = lds + wid * 8192;
    const unsigned short* SA = Apk + (size_t)(mt * 8 + wid) * 16384;
    const unsigned short* SB = Bpk + (size_t)(nt * 8 + wid) * 16384 + lane * 8;

    // per-lane fragment granule byte-offsets (shared by A-global and B-LDS reads)
    int gfrag[4];
    #pragma unroll
    for (int f = 0; f < 4; ++f) {
        int row  = f * 16 + (lane & 15);
        int slot = ((lane >> 4) + (row >> 1)) & 3;
        gfrag[f] = (row * 4 + slot) * 8;
    }

    auto stage = [&](int kt) {          // 4 instrs, each 1KB contiguous
        short* d = wbase + (kt & 3) * 2048;
        #pragma unroll
        for (int i = 0; i < 4; ++i)
            GLD_LDS16(SB + kt * 2048 + i * 512, d + i * 512);
    };

    i32x4 af[8][4];
    i32x4 bfv[2][4];
    f32x4 acc[4][4] = {};

    auto dsread = [&](int kt) {
        const short* s = wbase + (kt & 3) * 2048;
        #pragma unroll
        for (int f = 0; f < 4; ++f)
            bfv[kt & 1][f] = *(const i32x4*)(s + gfrag[f]);
    };

    // ---- prologue: A gen0 (16 coalesced loads), stage B0..B3 ----
    #pragma unroll
    for (int kt = 0; kt < 4; ++kt)
        #pragma unroll
        for (int f = 0; f < 4; ++f)
            af[kt][f] = *(const i32x4*)(SA + kt * 2048 + gfrag[f]);
    stage(0); stage(1); stage(2); stage(3);
    asm volatile("s_waitcnt vmcnt(12)" ::: "memory");   // A gen0 + B0 done
    dsread(0);

    #pragma unroll
    for (int i = 0; i < 8; ++i) {
        // counted vmcnt: B(i+1) ready (and A gen1 by i=4)
        if (i <= 3)      asm volatile("s_waitcnt vmcnt(8)"  ::: "memory");
        else if (i == 4) asm volatile("s_waitcnt vmcnt(8)"  ::: "memory");
        else if (i == 5) asm volatile("s_waitcnt vmcnt(4)"  ::: "memory");
        else if (i == 6) asm volatile("s_waitcnt vmcnt(0)"  ::: "memory");
        // correction for i==3: A gen1 (16) + B-bufs in flight -> need B4 only
        if (i == 3)      asm volatile("s_waitcnt vmcnt(24)" ::: "memory");

        if (i < 7) dsread(i + 1);                        // pipelined one iter ahead
        if (i < 7) asm volatile("s_waitcnt lgkmcnt(4)" ::: "memory");  // iter i's frags ready
        else       asm volatile("s_waitcnt lgkmcnt(0)" ::: "memory");
        __builtin_amdgcn_sched_barrier(0);               // rule #18: pin MFMA after wait

        if (i == 2) {                                    // A gen1 (16 coalesced loads)
            #pragma unroll
            for (int kt = 4; kt < 8; ++kt)
                #pragma unroll
                for (int f = 0; f < 4; ++f)
                    af[kt][f] = *(const i32x4*)(SA + kt * 2048 + gfrag[f]);
        }
        if (i < 4) stage(i + 4);                         // WAR-safe: buf i&3 fully read

        __builtin_amdgcn_s_setprio(1);
        #pragma unroll
        for (int fm = 0; fm < 4; ++fm)
            #pragma unroll
            for (int fn = 0; fn < 4; ++fn)
                acc[fm][fn] = __builtin_amdgcn_mfma_f32_16x16x32_bf16(
                    __builtin_bit_cast(bf16x8, af[i][fm]),
                    __builtin_bit_cast(bf16x8, bfv[i & 1][fn]),
                    acc[fm][fn], 0, 0, 0);
        __builtin_amdgcn_s_setprio(0);
    }

    // ---- cross-wave reduction through (reused) LDS ----
    float* scr = (float*)lds;
    #pragma unroll
    for (int fm = 0; fm < 4; ++fm)
        #pragma unroll
        for (int fn = 0; fn < 4; ++fn)
            *(f32x4*)(scr + wid * 4096 + (fm * 4 + fn) * 256 + lane * 4) = acc[fm][fn];
    __syncthreads();

    f32x4 ss[2] = {};
    #pragma unroll
    for (int h = 0; h < 2; ++h)
        #pragma unroll
        for (int w = 0; w < 8; ++w)
            ss[h] += *(const f32x4*)(scr + w * 4096 + (wid + h * 8) * 256 + lane * 4);

    const int w_hi  = n0 >> 8;              // pack w-index of this n-range
    const int kt0   = (n0 >> 5) & 7;        // first (even) kt chunk; block covers kt0,kt0+1
    const size_t chunk_base = ((size_t)(mt * 8 + w_hi) * 8 + kt0) * 2048;

    if (PHASE == 1) {
        // stage packed bf16 image in LDS, then fully-coalesced 16B/thread store
        __syncthreads();                    // all reduction reads of scr done
        unsigned short* img = (unsigned short*)lds;
        #pragma unroll
        for (int h = 0; h < 2; ++h) {
            int j  = wid + h * 8;
            int fm = j >> 2, fn = j & 3;
            #pragma unroll
            for (int r = 0; r < 4; ++r) {
                int row  = fm * 16 + ((lane >> 4) << 2) + r;
                int nl   = fn * 16 + (lane & 15);
                int kg   = n0 + nl;
                int slot = (((kg >> 3) & 3) + (row >> 1)) & 3;
                img[(nl >> 5) * 2048 + (row * 4 + slot) * 8 + (kg & 7)] = f2bf(ss[h][r]);
            }
        }
        __syncthreads();
        *(i32x4*)(w1pk + chunk_base + tid * 8) = *(const i32x4*)(img + tid * 8);
    } else {
        // degree-2 Chebyshev-node interpolation of exp(-s) on [0, 0.42*t]
        float tt = fmaxf(tptr[0], 1e-8f);
        float T  = 0.42f * tt;
        float c0, c1, c2;
        if (T < 1e-3f) { c0 = 1.0f; c1 = -1.0f; c2 = 0.5f; }
        else {
            float sa = T * 0.9330127f, sm = T * 0.5f, sc = T * 0.0669873f;
            float fa_ = __expf(-sa), fm_ = __expf(-sm), fc = __expf(-sc);
            float d01  = (fa_ - fm_) / (sa - sm);
            float d12  = (fm_ - fc) / (sm - sc);
            float d012 = (d01 - d12) / (sa - sc);
            c2 = d012;
            c1 = d01 - d012 * (sa + sm);
            c0 = fa_ - d01 * sa + d012 * sa * sm;
        }
        const float C1 = c1 * tt;
        const float C2 = c2 * tt * tt;

        __syncthreads();                    // all reduction reads of scr done
        float (*ot)[68] = (float (*)[68])lds;                 // bytes 0..17.4KB
        unsigned short* img = (unsigned short*)lds + 16384;   // bytes 32768..40960
        // bulk-load this block's w1 window (2 contiguous 4KB chunks) into LDS
        *(i32x4*)(img + tid * 8) = *(const i32x4*)(Apk + chunk_base + tid * 8);
        __syncthreads();
        #pragma unroll
        for (int h = 0; h < 2; ++h) {
            int j  = wid + h * 8;
            int fm = j >> 2, fn = j & 3;
            #pragma unroll
            for (int r = 0; r < 4; ++r) {
                int row  = fm * 16 + ((lane >> 4) << 2) + r;
                int nl   = fn * 16 + (lane & 15);
                int kg   = n0 + nl;
                int slot = (((kg >> 3) & 3) + (row >> 1)) & 3;
                float w1v = bf2f(img[(nl >> 5) * 2048 + (row * 4 + slot) * 8 + (kg & 7)]);
                ot[nl][row] = C1 * w1v + C2 * ss[h][r];
            }
        }
        __syncthreads();
        #pragma unroll
        for (int rr = 0; rr < 2; ++rr) {
            int e    = rr * 512 + tid;
            int nloc = e >> 4, mq = e & 15;
            f32x4 v  = *(const f32x4*)&ot[nloc][mq * 4];
            f32x4 xv = *(const f32x4*)(xin + (size_t)(n0 + nloc) * CC + m0 + mq * 4);
            #pragma unroll
            for (int q = 0; q < 4; ++q) v[q] += c0 * xv[q];
            *(f32x4*)(out + (size_t)(n0 + nloc) * CC + m0 + mq * 4) = v;
        }
    }
}

extern "C" void kernel_launch(void* const* d_in, const int* in_sizes, int n_in,
                              void* d_out, int out_size, void* d_ws, size_t ws_size,
                              hipStream_t stream) {
    (void)in_sizes; (void)n_in; (void)out_size; (void)ws_size;
    const float* x = (const float*)d_in[0];
    const float* L = (const float*)d_in[1];
    const float* t = (const float*)d_in[2];
    float* out = (float*)d_out;

    char* ws = (char*)d_ws;
    unsigned short* Lpack = (unsigned short*)ws;                   // 8 MB
    unsigned short* Apk1  = (unsigned short*)(ws + (8  << 20));    // 2 MB
    unsigned short* w1pk  = (unsigned short*)(ws + (10 << 20));    // 2 MB

    prep_kernel<<<320, 256, 0, stream>>>(L, Lpack, x, Apk1);
    gemm_step_kernel<1><<<256, 512, 0, stream>>>(Apk1, Lpack, nullptr, w1pk, nullptr, t);
    gemm_step_kernel<2><<<256, 512, 0, stream>>>(w1pk, Lpack, x,       nullptr, out,  t);
}

// Round 11
// 30.486 us; speedup vs baseline: 1.0492x; 1.0492x over previous
//
#include <hip/hip_runtime.h>
#include <hip/hip_bf16.h>

#define NN 2048   // n_nodes
#define CC 512    // channels

typedef __bf16 bf16x8 __attribute__((ext_vector_type(8)));
typedef float  f32x4  __attribute__((ext_vector_type(4)));
typedef int    i32x4  __attribute__((ext_vector_type(4)));
typedef unsigned short u16x4 __attribute__((ext_vector_type(4)));

#define GLD_LDS16(gptr, lptr)                                                        \
    __builtin_amdgcn_global_load_lds(                                                \
        (const __attribute__((address_space(1))) void*)(gptr),                       \
        (__attribute__((address_space(3))) void*)(lptr), 16, 0, 0)

__device__ __forceinline__ unsigned short f2bf(float f) {
    unsigned int u = __builtin_bit_cast(unsigned int, f);
    u += 0x7FFFu + ((u >> 16) & 1u);
    return (unsigned short)(u >> 16);
}
__device__ __forceinline__ float bf2f(unsigned short u) {
    unsigned int v = (unsigned int)u << 16;
    return __builtin_bit_cast(float, v);
}

// Packed operand layout = exact LDS image the GEMM consumes:
//   pack[tile][w:8][kt:8][granule:256][8 shorts],  granule = row*4 + slot,
//   content(row,slot,e) = M[tile*64+row][w*256 + kt*32 + kb*8 + e],  kb = (slot-(row>>1))&3.

// ---- prep (unchanged from round 9): L -> Lpack (XCD-aligned), x -> Apack ----
__global__ __launch_bounds__(256)
void prep_kernel(const float* __restrict__ L, unsigned short* __restrict__ Lpack,
                 const float* __restrict__ x, unsigned short* __restrict__ Apack) {
    __shared__ unsigned short sbuf[256 * 72];   // 36 KB
    const int tid = threadIdx.x;
    if (blockIdx.x < 256) {
        unsigned short (*tile)[264] = (unsigned short(*)[264])sbuf;
        int j  = blockIdx.x >> 3;
        int nt = (blockIdx.x & 7) * 4 + (j & 3);
        int w  = j >> 2;
        #pragma unroll
        for (int it = 0; it < 16; ++it) {
            int r = it * 4 + (tid >> 6);
            int c = (tid & 63) * 4;
            f32x4 v = __builtin_nontemporal_load(
                (const f32x4*)(L + (size_t)(nt * 64 + r) * NN + w * 256 + c));
            u16x4 o;
            o[0] = f2bf(v[0]); o[1] = f2bf(v[1]); o[2] = f2bf(v[2]); o[3] = f2bf(v[3]);
            *(u16x4*)&tile[r][c] = o;
        }
        __syncthreads();
        unsigned short* outp = Lpack + (size_t)(nt * 8 + w) * 8 * 2048;
        int row = tid >> 2, slot = tid & 3;
        int kb  = (slot - (row >> 1)) & 3;
        #pragma unroll
        for (int kt = 0; kt < 8; ++kt) {
            i32x4 v = *(const i32x4*)&tile[row][kt * 32 + kb * 8];
            *(i32x4*)(outp + kt * 2048 + tid * 8) = v;
        }
    } else {
        unsigned short (*t2)[72] = (unsigned short(*)[72])sbuf;
        int b2 = blockIdx.x - 256;
        int mt = b2 >> 3, w = b2 & 7;
        #pragma unroll
        for (int it = 0; it < 16; ++it) {
            int r = it * 16 + (tid >> 4);
            int c = (tid & 15) * 4;
            f32x4 v = *(const f32x4*)(x + (size_t)(w * 256 + r) * CC + mt * 64 + c);
            t2[r][c] = f2bf(v[0]); t2[r][c + 1] = f2bf(v[1]);
            t2[r][c + 2] = f2bf(v[2]); t2[r][c + 3] = f2bf(v[3]);
        }
        __syncthreads();
        unsigned short* outp = Apack + (size_t)(mt * 8 + w) * 8 * 2048;
        int row = tid >> 2, slot = tid & 3;
        int kb  = (slot - (row >> 1)) & 3;
        #pragma unroll
        for (int kt = 0; kt < 8; ++kt) {
            unsigned short tmp[8];
            #pragma unroll
            for (int e = 0; e < 8; ++e) tmp[e] = t2[kt * 32 + kb * 8 + e][row];
            *(i32x4*)(outp + kt * 2048 + tid * 8) = *(const i32x4*)tmp;
        }
    }
}

// ---- GEMM w = v @ L, 64x64 tile, 8 waves with disjoint 256-wide K-chunks.
//      Main loop = round-9 exactly (best measured): per-wave A+B LDS double
//      buffer fed by contiguous 1KB global_load_lds, vmcnt(8) cadence, zero
//      barriers. Epilogues = round-10's coalesced versions (LDS-staged).
//      PHASE 1: w1pk = bf16(w)   (LDS image -> 16B/thread store)
//      PHASE 2: out[n][c] = c0*x + C1*w1 + C2*w2  (w1 via LDS bulk load) ----
template <int PHASE>
__global__ __launch_bounds__(512)
void gemm_step_kernel(const unsigned short* __restrict__ Apk,  // packed A [8][8][8][2048] (phase2: w1pk)
                      const unsigned short* __restrict__ Bpk,  // packed L [32][8][8][2048]
                      const float* __restrict__ xin,           // x [2048][512] (phase2)
                      unsigned short* __restrict__ w1pk,       // packed w1 out (phase1)
                      float* __restrict__ out,                 // [2048][512] (phase2)
                      const float* __restrict__ tptr) {
    __shared__ short lds[65536];   // 8 waves x 2 bufs x (A 4KB + B 4KB); reused in epilogue

    const int tid  = threadIdx.x;
    const int lane = tid & 63;
    const int wid  = tid >> 6;

    const int bid = blockIdx.x;
    const int xcd = bid & 7, idx = bid >> 3;
    const int n0  = (xcd * 4 + (idx & 3)) * 64;
    const int m0  = (idx >> 2) * 64;
    const int mt  = m0 >> 6, nt = n0 >> 6;

    short* wbase = lds + wid * 8192;    // this wave's 16KB
    const unsigned short* SA = Apk + (size_t)(mt * 8 + wid) * 16384 + lane * 8;
    const unsigned short* SB = Bpk + (size_t)(nt * 8 + wid) * 16384 + lane * 8;

    auto stage = [&](int kt) {          // 8 instrs, each 1KB contiguous
        short* d = wbase + (kt & 1) * 4096;
        #pragma unroll
        for (int i = 0; i < 4; ++i) {
            GLD_LDS16(SA + kt * 2048 + i * 512, d + i * 512);
            GLD_LDS16(SB + kt * 2048 + i * 512, d + 2048 + i * 512);
        }
    };

    i32x4 af[4], bfv[4];
    f32x4 acc[4][4] = {};

    stage(0); stage(1);
    #pragma unroll
    for (int i = 0; i < 8; ++i) {
        if (i < 7) asm volatile("s_waitcnt vmcnt(8)" ::: "memory");
        else       asm volatile("s_waitcnt vmcnt(0)" ::: "memory");
        const short* s = wbase + (i & 1) * 4096;
        #pragma unroll
        for (int f = 0; f < 4; ++f) {
            int row  = f * 16 + (lane & 15);
            int slot = ((lane >> 4) + (row >> 1)) & 3;
            int g    = row * 4 + slot;
            af[f]  = *(const i32x4*)(s + g * 8);
            bfv[f] = *(const i32x4*)(s + 2048 + g * 8);
        }
        asm volatile("s_waitcnt lgkmcnt(0)" ::: "memory");   // frags in regs -> WAR-safe restage
        if (i < 6) stage(i + 2);

        __builtin_amdgcn_s_setprio(1);
        #pragma unroll
        for (int fm = 0; fm < 4; ++fm)
            #pragma unroll
            for (int fn = 0; fn < 4; ++fn)
                acc[fm][fn] = __builtin_amdgcn_mfma_f32_16x16x32_bf16(
                    __builtin_bit_cast(bf16x8, af[fm]),
                    __builtin_bit_cast(bf16x8, bfv[fn]),
                    acc[fm][fn], 0, 0, 0);
        __builtin_amdgcn_s_setprio(0);
    }

    // ---- cross-wave reduction through (reused) LDS ----
    float* scr = (float*)lds;
    #pragma unroll
    for (int fm = 0; fm < 4; ++fm)
        #pragma unroll
        for (int fn = 0; fn < 4; ++fn)
            *(f32x4*)(scr + wid * 4096 + (fm * 4 + fn) * 256 + lane * 4) = acc[fm][fn];
    __syncthreads();

    f32x4 ss[2] = {};
    #pragma unroll
    for (int h = 0; h < 2; ++h)
        #pragma unroll
        for (int w = 0; w < 8; ++w)
            ss[h] += *(const f32x4*)(scr + w * 4096 + (wid + h * 8) * 256 + lane * 4);

    const int w_hi  = n0 >> 8;              // pack w-index of this n-range
    const int kt0   = (n0 >> 5) & 7;        // first (even) kt chunk; block covers kt0,kt0+1
    const size_t chunk_base = ((size_t)(mt * 8 + w_hi) * 8 + kt0) * 2048;

    if (PHASE == 1) {
        // stage packed bf16 image in LDS, then fully-coalesced 16B/thread store
        __syncthreads();                    // all reduction reads of scr done
        unsigned short* img = (unsigned short*)lds;
        #pragma unroll
        for (int h = 0; h < 2; ++h) {
            int j  = wid + h * 8;
            int fm = j >> 2, fn = j & 3;
            #pragma unroll
            for (int r = 0; r < 4; ++r) {
                int row  = fm * 16 + ((lane >> 4) << 2) + r;
                int nl   = fn * 16 + (lane & 15);
                int kg   = n0 + nl;
                int slot = (((kg >> 3) & 3) + (row >> 1)) & 3;
                img[(nl >> 5) * 2048 + (row * 4 + slot) * 8 + (kg & 7)] = f2bf(ss[h][r]);
            }
        }
        __syncthreads();
        *(i32x4*)(w1pk + chunk_base + tid * 8) = *(const i32x4*)(img + tid * 8);
    } else {
        // degree-2 Chebyshev-node interpolation of exp(-s) on [0, 0.42*t]
        float tt = fmaxf(tptr[0], 1e-8f);
        float T  = 0.42f * tt;
        float c0, c1, c2;
        if (T < 1e-3f) { c0 = 1.0f; c1 = -1.0f; c2 = 0.5f; }
        else {
            float sa = T * 0.9330127f, sm = T * 0.5f, sc = T * 0.0669873f;
            float fa_ = __expf(-sa), fm_ = __expf(-sm), fc = __expf(-sc);
            float d01  = (fa_ - fm_) / (sa - sm);
            float d12  = (fm_ - fc) / (sm - sc);
            float d012 = (d01 - d12) / (sa - sc);
            c2 = d012;
            c1 = d01 - d012 * (sa + sm);
            c0 = fa_ - d01 * sa + d012 * sa * sm;
        }
        const float C1 = c1 * tt;
        const float C2 = c2 * tt * tt;

        __syncthreads();                    // all reduction reads of scr done
        float (*ot)[68] = (float (*)[68])lds;                 // bytes 0..17.4KB
        unsigned short* img = (unsigned short*)lds + 16384;   // bytes 32768..40960
        // bulk-load this block's w1 window (2 contiguous 4KB chunks) into LDS
        *(i32x4*)(img + tid * 8) = *(const i32x4*)(Apk + chunk_base + tid * 8);
        __syncthreads();
        #pragma unroll
        for (int h = 0; h < 2; ++h) {
            int j  = wid + h * 8;
            int fm = j >> 2, fn = j & 3;
            #pragma unroll
            for (int r = 0; r < 4; ++r) {
                int row  = fm * 16 + ((lane >> 4) << 2) + r;
                int nl   = fn * 16 + (lane & 15);
                int kg   = n0 + nl;
                int slot = (((kg >> 3) & 3) + (row >> 1)) & 3;
                float w1v = bf2f(img[(nl >> 5) * 2048 + (row * 4 + slot) * 8 + (kg & 7)]);
                ot[nl][row] = C1 * w1v + C2 * ss[h][r];
            }
        }
        __syncthreads();
        #pragma unroll
        for (int rr = 0; rr < 2; ++rr) {
            int e    = rr * 512 + tid;
            int nloc = e >> 4, mq = e & 15;
            f32x4 v  = *(const f32x4*)&ot[nloc][mq * 4];
            f32x4 xv = *(const f32x4*)(xin + (size_t)(n0 + nloc) * CC + m0 + mq * 4);
            #pragma unroll
            for (int q = 0; q < 4; ++q) v[q] += c0 * xv[q];
            *(f32x4*)(out + (size_t)(n0 + nloc) * CC + m0 + mq * 4) = v;
        }
    }
}

extern "C" void kernel_launch(void* const* d_in, const int* in_sizes, int n_in,
                              void* d_out, int out_size, void* d_ws, size_t ws_size,
                              hipStream_t stream) {
    (void)in_sizes; (void)n_in; (void)out_size; (void)ws_size;
    const float* x = (const float*)d_in[0];
    const float* L = (const float*)d_in[1];
    const float* t = (const float*)d_in[2];
    float* out = (float*)d_out;

    char* ws = (char*)d_ws;
    unsigned short* Lpack = (unsigned short*)ws;                   // 8 MB
    unsigned short* Apk1  = (unsigned short*)(ws + (8  << 20));    // 2 MB
    unsigned short* w1pk  = (unsigned short*)(ws + (10 << 20));    // 2 MB

    prep_kernel<<<320, 256, 0, stream>>>(L, Lpack, x, Apk1);
    gemm_step_kernel<1><<<256, 512, 0, stream>>>(Apk1, Lpack, nullptr, w1pk, nullptr, t);
    gemm_step_kernel<2><<<256, 512, 0, stream>>>(w1pk, Lpack, x,       nullptr, out,  t);
}